// Round 1
// baseline (335.476 us; speedup 1.0000x reference)
//
#include <hip/hip_runtime.h>
#include <hip/hip_bf16.h>
#include <stdint.h>

typedef __attribute__((ext_vector_type(8))) __bf16 bf16x8;
typedef __attribute__((ext_vector_type(4))) float f32x4;
typedef __attribute__((ext_vector_type(8))) unsigned short ushort8;
typedef __attribute__((ext_vector_type(4))) unsigned short ushort4v;

__device__ __forceinline__ unsigned short bfbits(float x) {
    __bf16 b = (__bf16)x;
    return __builtin_bit_cast(unsigned short, b);
}

__device__ __forceinline__ f32x4 mfma_bf16(bf16x8 a, bf16x8 b, f32x4 c) {
    return __builtin_amdgcn_mfma_f32_16x16x32_bf16(a, b, c, 0, 0, 0);
}

// ---------------------------------------------------------------------------
// GEMM: Y[m,n] = sum_k A[m,k] * W[n,k] + bias[n]   (M=8192, N=512, K=512)
// A_IS_F32: A is fp32 (convert to bf16 during staging) else bf16.
// OUT_MODE: 0 = bf16 head-layout [bh][s][64]
//           1 = bf16 transposed V layout [bh][64][s]
//           2 = fp32 flat [m][512]
// ---------------------------------------------------------------------------
template<int A_IS_F32, int OUT_MODE>
__global__ __launch_bounds__(256) void gemm_512(
    const void* __restrict__ Aptr, const float* __restrict__ W,
    const float* __restrict__ bias, void* __restrict__ Out)
{
    __shared__ unsigned short Alds[128][40];  // +8 pad: frag reads ~2-way max
    __shared__ unsigned short Blds[128][40];

    const int tid  = threadIdx.x;
    const int lane = tid & 63;
    const int wid  = tid >> 6;
    const int wm   = wid >> 1, wn = wid & 1;   // 2x2 waves, 64x64 each
    const int bm   = blockIdx.y, bn = blockIdx.x;
    const int l15  = lane & 15;
    const int g    = lane >> 4;

    const int srow = tid >> 1;
    const int scol = (tid & 1) * 16;

    f32x4 acc[4][4];
    #pragma unroll
    for (int m = 0; m < 4; m++)
        #pragma unroll
        for (int n = 0; n < 4; n++)
            acc[m][n] = (f32x4){0.f, 0.f, 0.f, 0.f};

    for (int k0 = 0; k0 < 512; k0 += 32) {
        // ---- stage A tile (128x32) ----
        if (A_IS_F32) {
            const float* A = (const float*)Aptr + (size_t)(bm * 128 + srow) * 512 + k0 + scol;
            float4 v0 = ((const float4*)A)[0];
            float4 v1 = ((const float4*)A)[1];
            float4 v2 = ((const float4*)A)[2];
            float4 v3 = ((const float4*)A)[3];
            ushort8 p0 = { bfbits(v0.x), bfbits(v0.y), bfbits(v0.z), bfbits(v0.w),
                           bfbits(v1.x), bfbits(v1.y), bfbits(v1.z), bfbits(v1.w) };
            ushort8 p1 = { bfbits(v2.x), bfbits(v2.y), bfbits(v2.z), bfbits(v2.w),
                           bfbits(v3.x), bfbits(v3.y), bfbits(v3.z), bfbits(v3.w) };
            *(ushort8*)&Alds[srow][scol]     = p0;
            *(ushort8*)&Alds[srow][scol + 8] = p1;
        } else {
            const unsigned short* A = (const unsigned short*)Aptr + (size_t)(bm * 128 + srow) * 512 + k0 + scol;
            ushort8 p0 = ((const ushort8*)A)[0];
            ushort8 p1 = ((const ushort8*)A)[1];
            *(ushort8*)&Alds[srow][scol]     = p0;
            *(ushort8*)&Alds[srow][scol + 8] = p1;
        }
        // ---- stage B tile (W rows, fp32 -> bf16) ----
        {
            const float* Bp = W + (size_t)(bn * 128 + srow) * 512 + k0 + scol;
            float4 v0 = ((const float4*)Bp)[0];
            float4 v1 = ((const float4*)Bp)[1];
            float4 v2 = ((const float4*)Bp)[2];
            float4 v3 = ((const float4*)Bp)[3];
            ushort8 p0 = { bfbits(v0.x), bfbits(v0.y), bfbits(v0.z), bfbits(v0.w),
                           bfbits(v1.x), bfbits(v1.y), bfbits(v1.z), bfbits(v1.w) };
            ushort8 p1 = { bfbits(v2.x), bfbits(v2.y), bfbits(v2.z), bfbits(v2.w),
                           bfbits(v3.x), bfbits(v3.y), bfbits(v3.z), bfbits(v3.w) };
            *(ushort8*)&Blds[srow][scol]     = p0;
            *(ushort8*)&Blds[srow][scol + 8] = p1;
        }
        __syncthreads();

        bf16x8 af[4], bfr[4];
        #pragma unroll
        for (int m = 0; m < 4; m++)
            af[m] = *(const bf16x8*)&Alds[wm * 64 + m * 16 + l15][g * 8];
        #pragma unroll
        for (int n = 0; n < 4; n++)
            bfr[n] = *(const bf16x8*)&Blds[wn * 64 + n * 16 + l15][g * 8];
        #pragma unroll
        for (int m = 0; m < 4; m++)
            #pragma unroll
            for (int n = 0; n < 4; n++)
                acc[m][n] = mfma_bf16(af[m], bfr[n], acc[m][n]);
        __syncthreads();
    }

    // ---- epilogue ----
    #pragma unroll
    for (int m = 0; m < 4; m++) {
        const int grow0 = bm * 128 + wm * 64 + m * 16 + (g << 2);  // + reg
        #pragma unroll
        for (int n = 0; n < 4; n++) {
            const int gcol = bn * 128 + wn * 64 + n * 16 + l15;
            const float bv = bias[gcol];
            f32x4 c = acc[m][n];
            if (OUT_MODE == 2) {
                float* O = (float*)Out;
                #pragma unroll
                for (int r = 0; r < 4; r++)
                    O[(size_t)(grow0 + r) * 512 + gcol] = c[r] + bv;
            } else if (OUT_MODE == 0) {
                unsigned short* O = (unsigned short*)Out;
                const int b = grow0 >> 12, s0 = grow0 & 4095;
                const int h = gcol >> 6, dk = gcol & 63;
                const size_t base = ((size_t)(b * 8 + h) * 4096 + s0) * 64 + dk;
                #pragma unroll
                for (int r = 0; r < 4; r++)
                    O[base + (size_t)r * 64] = bfbits(c[r] + bv);
            } else {
                unsigned short* O = (unsigned short*)Out;
                const int b = grow0 >> 12, s0 = grow0 & 4095;
                const int h = gcol >> 6, dk = gcol & 63;
                ushort4v pk = { bfbits(c[0] + bv), bfbits(c[1] + bv),
                                bfbits(c[2] + bv), bfbits(c[3] + bv) };
                *(ushort4v*)&O[((size_t)(b * 8 + h) * 64 + dk) * 4096 + s0] = pk;
            }
        }
    }
}

// ---------------------------------------------------------------------------
// Flash attention with multiplicative positional decay on scores.
// Grid: 1024 blocks = 16 (b,h) x 64 q-tiles of 64 rows; 4 waves x 16 q-rows.
// ---------------------------------------------------------------------------
__global__ __launch_bounds__(256) void attn_decay(
    const unsigned short* __restrict__ Qh, const unsigned short* __restrict__ Kh,
    const unsigned short* __restrict__ Vt, const float* __restrict__ time_decay,
    const float* __restrict__ scale_p, unsigned short* __restrict__ ctx)
{
    __shared__ char Klds[8192];        // 64 keys x 128B, XOR-swizzled
    __shared__ char Vlds[8192];        // 64 d    x 128B, XOR-swizzled
    __shared__ char Plds[4][2048];     // per-wave 16 rows x 128B, XOR-swizzled

    const int tid  = threadIdx.x;
    const int lane = tid & 63;
    const int w    = tid >> 6;
    const int i    = blockIdx.x;
    // XCD swizzle (bijective, 1024 % 8 == 0): each XCD sees exactly 2 heads
    const int bh = ((i & 7) << 1) | ((i >> 9) & 1);
    const int qt = (i >> 3) & 63;
    const int h  = bh & 7;
    const int b  = bh >> 3;

    const int l15 = lane & 15;
    const int g   = lane >> 4;

    const float td   = time_decay[h];
    const float coef = scale_p[0] * 0.125f;  // scale / sqrt(64)

    // Q fragments (16 rows x 64 d per wave), held in registers
    bf16x8 aq0, aq1;
    {
        const unsigned short* Qp = Qh + (((size_t)bh * 4096) + qt * 64 + w * 16 + l15) * 64 + g * 8;
        aq0 = *(const bf16x8*)Qp;
        aq1 = *(const bf16x8*)(Qp + 32);
    }

    f32x4 o[4];
    #pragma unroll
    for (int d = 0; d < 4; d++) o[d] = (f32x4){0.f, 0.f, 0.f, 0.f};
    float mrow[4] = {-3e38f, -3e38f, -3e38f, -3e38f};
    float lrow[4] = {0.f, 0.f, 0.f, 0.f};

    const size_t kbase = (size_t)bh * 4096 * 64;
    const size_t vbase = (size_t)bh * 64 * 4096;

    for (int kt = 0; kt < 64; ++kt) {
        // ---- stage K tile (contiguous 8KB) with XOR swizzle ----
        {
            const char* src = (const char*)(Kh + kbase + (size_t)kt * 64 * 64) + tid * 32;
            uint4 a  = *(const uint4*)src;
            uint4 bb = *(const uint4*)(src + 16);
            const int r = tid >> 2;
            const int c = (tid & 3) * 32;
            const int sw = (r & 7) << 4;
            *(uint4*)(Klds + r * 128 + (c ^ sw))        = a;
            *(uint4*)(Klds + r * 128 + ((c + 16) ^ sw)) = bb;
        }
        // ---- stage V tile (64 rows of Vt, 128B each) ----
        {
            const int r = tid >> 2;
            const int c = (tid & 3) * 32;
            const char* src = (const char*)(Vt + vbase + (size_t)r * 4096 + kt * 64) + c;
            uint4 a  = *(const uint4*)src;
            uint4 bb = *(const uint4*)(src + 16);
            const int sw = (r & 7) << 4;
            *(uint4*)(Vlds + r * 128 + (c ^ sw))        = a;
            *(uint4*)(Vlds + r * 128 + ((c + 16) ^ sw)) = bb;
        }
        __syncthreads();

        // ---- S = Q K^T (16 x 64 per wave) ----
        f32x4 s[4];
        #pragma unroll
        for (int n = 0; n < 4; n++) {
            const int r = n * 16 + l15;
            const int sw = (r & 7) << 4;
            bf16x8 k0 = *(const bf16x8*)(Klds + r * 128 + ((g * 16) ^ sw));
            bf16x8 k1 = *(const bf16x8*)(Klds + r * 128 + ((64 + g * 16) ^ sw));
            f32x4 z = (f32x4){0.f, 0.f, 0.f, 0.f};
            z = mfma_bf16(aq0, k0, z);
            z = mfma_bf16(aq1, k1, z);
            s[n] = z;
        }

        // ---- decay + online softmax ----
        float fac[4];
        #pragma unroll
        for (int n = 0; n < 4; n++)
            fac[n] = coef * __expf(-td * (float)(kt * 64 + n * 16 + l15));

        float sv[4][4];
        float tmax[4] = {-3e38f, -3e38f, -3e38f, -3e38f};
        #pragma unroll
        for (int n = 0; n < 4; n++)
            #pragma unroll
            for (int r = 0; r < 4; r++) {
                float v = s[n][r] * fac[n];
                sv[n][r] = v;
                tmax[r] = fmaxf(tmax[r], v);
            }
        float alpha[4], tsum[4];
        #pragma unroll
        for (int r = 0; r < 4; r++) {
            float t = tmax[r];
            t = fmaxf(t, __shfl_xor(t, 1));
            t = fmaxf(t, __shfl_xor(t, 2));
            t = fmaxf(t, __shfl_xor(t, 4));
            t = fmaxf(t, __shfl_xor(t, 8));
            float mnew = fmaxf(mrow[r], t);
            alpha[r] = __expf(mrow[r] - mnew);
            mrow[r] = mnew;
            tsum[r] = 0.f;
        }
        unsigned short pb[4][4];
        #pragma unroll
        for (int n = 0; n < 4; n++)
            #pragma unroll
            for (int r = 0; r < 4; r++) {
                float p = __expf(sv[n][r] - mrow[r]);
                tsum[r] += p;
                pb[n][r] = bfbits(p);
            }
        #pragma unroll
        for (int r = 0; r < 4; r++) {
            float t = tsum[r];
            t += __shfl_xor(t, 1);
            t += __shfl_xor(t, 2);
            t += __shfl_xor(t, 4);
            t += __shfl_xor(t, 8);
            lrow[r] = lrow[r] * alpha[r] + t;
        }
        #pragma unroll
        for (int d = 0; d < 4; d++)
            #pragma unroll
            for (int r = 0; r < 4; r++)
                o[d][r] *= alpha[r];

        // ---- P -> per-wave LDS (swizzled), then PV ----
        char* pw = Plds[w];
        #pragma unroll
        for (int r = 0; r < 4; r++) {
            const int row = g * 4 + r;
            const int sw = (row & 7) << 4;
            #pragma unroll
            for (int n = 0; n < 4; n++) {
                const int cb = (n * 16 + l15) * 2;
                *(unsigned short*)(pw + row * 128 + (cb ^ sw)) = pb[n][r];
            }
        }
        {
            const int row = l15;
            const int sw = (row & 7) << 4;
            bf16x8 pa0 = *(const bf16x8*)(pw + row * 128 + ((g * 16) ^ sw));
            bf16x8 pa1 = *(const bf16x8*)(pw + row * 128 + ((64 + g * 16) ^ sw));
            #pragma unroll
            for (int d = 0; d < 4; d++) {
                const int vr = d * 16 + l15;
                const int vsw = (vr & 7) << 4;
                bf16x8 v0 = *(const bf16x8*)(Vlds + vr * 128 + ((g * 16) ^ vsw));
                bf16x8 v1 = *(const bf16x8*)(Vlds + vr * 128 + ((64 + g * 16) ^ vsw));
                o[d] = mfma_bf16(pa0, v0, o[d]);
                o[d] = mfma_bf16(pa1, v1, o[d]);
            }
        }
        __syncthreads();
    }

    // ---- normalize and write ctx[b][s][h*64+d] as bf16 ----
    float inv[4];
    #pragma unroll
    for (int r = 0; r < 4; r++) inv[r] = 1.f / lrow[r];
    #pragma unroll
    for (int d = 0; d < 4; d++)
        #pragma unroll
        for (int r = 0; r < 4; r++) {
            const int srow_ = qt * 64 + w * 16 + g * 4 + r;
            const size_t idx = ((size_t)b * 4096 + srow_) * 512 + h * 64 + d * 16 + l15;
            ctx[idx] = bfbits(o[d][r] * inv[r]);
        }
}

// ---------------------------------------------------------------------------
extern "C" void kernel_launch(void* const* d_in, const int* in_sizes, int n_in,
                              void* d_out, int out_size, void* d_ws, size_t ws_size,
                              hipStream_t stream)
{
    (void)in_sizes; (void)n_in; (void)out_size; (void)ws_size;
    const float* q  = (const float*)d_in[0];
    const float* k  = (const float*)d_in[1];
    const float* v  = (const float*)d_in[2];
    const float* Wq = (const float*)d_in[3];
    const float* bq = (const float*)d_in[4];
    const float* Wk = (const float*)d_in[5];
    const float* bk = (const float*)d_in[6];
    const float* Wv = (const float*)d_in[7];
    const float* bv = (const float*)d_in[8];
    const float* Wo = (const float*)d_in[9];
    const float* bo = (const float*)d_in[10];
    const float* td = (const float*)d_in[11];
    const float* sc = (const float*)d_in[12];

    // workspace: Qh, Kh, Vt, ctx — 8 MB each (bf16), 32 MB total
    unsigned short* Qh  = (unsigned short*)d_ws;
    unsigned short* Kh  = Qh + (size_t)16 * 4096 * 64;
    unsigned short* Vt  = Kh + (size_t)16 * 4096 * 64;
    unsigned short* ctx = Vt + (size_t)16 * 4096 * 64;

    dim3 gg(4, 64), bb(256);
    gemm_512<1, 0><<<gg, bb, 0, stream>>>(q, Wq, bq, Qh);
    gemm_512<1, 0><<<gg, bb, 0, stream>>>(k, Wk, bk, Kh);
    gemm_512<1, 1><<<gg, bb, 0, stream>>>(v, Wv, bv, Vt);
    attn_decay<<<dim3(1024), bb, 0, stream>>>(Qh, Kh, Vt, td, sc, ctx);
    gemm_512<0, 2><<<gg, bb, 0, stream>>>(ctx, Wo, bo, (float*)d_out);
}

// Round 2
// 186.749 us; speedup vs baseline: 1.7964x; 1.7964x over previous
//
#include <hip/hip_runtime.h>
#include <hip/hip_bf16.h>
#include <stdint.h>

typedef __attribute__((ext_vector_type(8))) __bf16 bf16x8;
typedef __attribute__((ext_vector_type(4))) float f32x4;
typedef __attribute__((ext_vector_type(8))) unsigned short ushort8;
typedef __attribute__((ext_vector_type(4))) unsigned short ushort4v;

__device__ __forceinline__ unsigned short bfbits(float x) {
    __bf16 b = (__bf16)x;
    return __builtin_bit_cast(unsigned short, b);
}

__device__ __forceinline__ f32x4 mfma_bf16(bf16x8 a, bf16x8 b, f32x4 c) {
    return __builtin_amdgcn_mfma_f32_16x16x32_bf16(a, b, c, 0, 0, 0);
}

// async global->LDS, 16B per lane. Global src is PER-LANE, LDS dest is
// wave-uniform base + lane*16 (hardware adds the lane offset).
__device__ __forceinline__ void gload16(const void* g, void* l) {
    __builtin_amdgcn_global_load_lds(
        (const __attribute__((address_space(1))) unsigned int*)g,
        (__attribute__((address_space(3))) unsigned int*)l, 16, 0, 0);
}

// ---------------------------------------------------------------------------
// Merged Q/K/V projection GEMM: blockIdx.z selects which projection.
// Y[m,n] = sum_k A[m,k] * W[n,k] + bias[n]   (M=8192, N=512, K=512), A fp32.
// z=0 -> Qh bf16 [bh][s][64]; z=1 -> Kh same; z=2 -> Vt bf16 [bh][64][s].
// ---------------------------------------------------------------------------
__global__ __launch_bounds__(256) void gemm_qkv(
    const float* __restrict__ q, const float* __restrict__ k, const float* __restrict__ v,
    const float* __restrict__ Wq, const float* __restrict__ bq,
    const float* __restrict__ Wk, const float* __restrict__ bk,
    const float* __restrict__ Wv, const float* __restrict__ bv,
    unsigned short* __restrict__ Qh, unsigned short* __restrict__ Kh,
    unsigned short* __restrict__ Vt)
{
    __shared__ unsigned short Alds[128][40];
    __shared__ unsigned short Blds[128][40];

    const int z = blockIdx.z;
    const float* A0   = (z == 0) ? q  : (z == 1) ? k  : v;
    const float* W    = (z == 0) ? Wq : (z == 1) ? Wk : Wv;
    const float* bias = (z == 0) ? bq : (z == 1) ? bk : bv;

    const int tid  = threadIdx.x;
    const int lane = tid & 63;
    const int wid  = tid >> 6;
    const int wm   = wid >> 1, wn = wid & 1;
    const int bm   = blockIdx.y, bn = blockIdx.x;
    const int l15  = lane & 15;
    const int g    = lane >> 4;
    const int srow = tid >> 1;
    const int scol = (tid & 1) * 16;

    f32x4 acc[4][4];
    #pragma unroll
    for (int m = 0; m < 4; m++)
        #pragma unroll
        for (int n = 0; n < 4; n++)
            acc[m][n] = (f32x4){0.f, 0.f, 0.f, 0.f};

    for (int k0 = 0; k0 < 512; k0 += 32) {
        {
            const float* A = A0 + (size_t)(bm * 128 + srow) * 512 + k0 + scol;
            float4 v0 = ((const float4*)A)[0];
            float4 v1 = ((const float4*)A)[1];
            float4 v2 = ((const float4*)A)[2];
            float4 v3 = ((const float4*)A)[3];
            ushort8 p0 = { bfbits(v0.x), bfbits(v0.y), bfbits(v0.z), bfbits(v0.w),
                           bfbits(v1.x), bfbits(v1.y), bfbits(v1.z), bfbits(v1.w) };
            ushort8 p1 = { bfbits(v2.x), bfbits(v2.y), bfbits(v2.z), bfbits(v2.w),
                           bfbits(v3.x), bfbits(v3.y), bfbits(v3.z), bfbits(v3.w) };
            *(ushort8*)&Alds[srow][scol]     = p0;
            *(ushort8*)&Alds[srow][scol + 8] = p1;
        }
        {
            const float* Bp = W + (size_t)(bn * 128 + srow) * 512 + k0 + scol;
            float4 v0 = ((const float4*)Bp)[0];
            float4 v1 = ((const float4*)Bp)[1];
            float4 v2 = ((const float4*)Bp)[2];
            float4 v3 = ((const float4*)Bp)[3];
            ushort8 p0 = { bfbits(v0.x), bfbits(v0.y), bfbits(v0.z), bfbits(v0.w),
                           bfbits(v1.x), bfbits(v1.y), bfbits(v1.z), bfbits(v1.w) };
            ushort8 p1 = { bfbits(v2.x), bfbits(v2.y), bfbits(v2.z), bfbits(v2.w),
                           bfbits(v3.x), bfbits(v3.y), bfbits(v3.z), bfbits(v3.w) };
            *(ushort8*)&Blds[srow][scol]     = p0;
            *(ushort8*)&Blds[srow][scol + 8] = p1;
        }
        __syncthreads();

        bf16x8 af[4], bfr[4];
        #pragma unroll
        for (int m = 0; m < 4; m++)
            af[m] = *(const bf16x8*)&Alds[wm * 64 + m * 16 + l15][g * 8];
        #pragma unroll
        for (int n = 0; n < 4; n++)
            bfr[n] = *(const bf16x8*)&Blds[wn * 64 + n * 16 + l15][g * 8];
        #pragma unroll
        for (int m = 0; m < 4; m++)
            #pragma unroll
            for (int n = 0; n < 4; n++)
                acc[m][n] = mfma_bf16(af[m], bfr[n], acc[m][n]);
        __syncthreads();
    }

    #pragma unroll
    for (int m = 0; m < 4; m++) {
        const int grow0 = bm * 128 + wm * 64 + m * 16 + (g << 2);
        #pragma unroll
        for (int n = 0; n < 4; n++) {
            const int gcol = bn * 128 + wn * 64 + n * 16 + l15;
            const float bv2 = bias[gcol];
            f32x4 c = acc[m][n];
            const int b = grow0 >> 12, s0 = grow0 & 4095;
            const int h = gcol >> 6, dk = gcol & 63;
            if (z < 2) {
                unsigned short* O = z ? Kh : Qh;
                const size_t base = ((size_t)(b * 8 + h) * 4096 + s0) * 64 + dk;
                #pragma unroll
                for (int r = 0; r < 4; r++)
                    O[base + (size_t)r * 64] = bfbits(c[r] + bv2);
            } else {
                ushort4v pk = { bfbits(c[0] + bv2), bfbits(c[1] + bv2),
                                bfbits(c[2] + bv2), bfbits(c[3] + bv2) };
                *(ushort4v*)&Vt[((size_t)(b * 8 + h) * 64 + dk) * 4096 + s0] = pk;
            }
        }
    }
}

// ---------------------------------------------------------------------------
// Output projection GEMM: A = ctx bf16 [8192][512], out fp32.
// ---------------------------------------------------------------------------
__global__ __launch_bounds__(256) void gemm_out(
    const unsigned short* __restrict__ Actx, const float* __restrict__ W,
    const float* __restrict__ bias, float* __restrict__ Out)
{
    __shared__ unsigned short Alds[128][40];
    __shared__ unsigned short Blds[128][40];

    const int tid  = threadIdx.x;
    const int lane = tid & 63;
    const int wid  = tid >> 6;
    const int wm   = wid >> 1, wn = wid & 1;
    const int bm   = blockIdx.y, bn = blockIdx.x;
    const int l15  = lane & 15;
    const int g    = lane >> 4;
    const int srow = tid >> 1;
    const int scol = (tid & 1) * 16;

    f32x4 acc[4][4];
    #pragma unroll
    for (int m = 0; m < 4; m++)
        #pragma unroll
        for (int n = 0; n < 4; n++)
            acc[m][n] = (f32x4){0.f, 0.f, 0.f, 0.f};

    for (int k0 = 0; k0 < 512; k0 += 32) {
        {
            const unsigned short* A = Actx + (size_t)(bm * 128 + srow) * 512 + k0 + scol;
            ushort8 p0 = ((const ushort8*)A)[0];
            ushort8 p1 = ((const ushort8*)A)[1];
            *(ushort8*)&Alds[srow][scol]     = p0;
            *(ushort8*)&Alds[srow][scol + 8] = p1;
        }
        {
            const float* Bp = W + (size_t)(bn * 128 + srow) * 512 + k0 + scol;
            float4 v0 = ((const float4*)Bp)[0];
            float4 v1 = ((const float4*)Bp)[1];
            float4 v2 = ((const float4*)Bp)[2];
            float4 v3 = ((const float4*)Bp)[3];
            ushort8 p0 = { bfbits(v0.x), bfbits(v0.y), bfbits(v0.z), bfbits(v0.w),
                           bfbits(v1.x), bfbits(v1.y), bfbits(v1.z), bfbits(v1.w) };
            ushort8 p1 = { bfbits(v2.x), bfbits(v2.y), bfbits(v2.z), bfbits(v2.w),
                           bfbits(v3.x), bfbits(v3.y), bfbits(v3.z), bfbits(v3.w) };
            *(ushort8*)&Blds[srow][scol]     = p0;
            *(ushort8*)&Blds[srow][scol + 8] = p1;
        }
        __syncthreads();

        bf16x8 af[4], bfr[4];
        #pragma unroll
        for (int m = 0; m < 4; m++)
            af[m] = *(const bf16x8*)&Alds[wm * 64 + m * 16 + l15][g * 8];
        #pragma unroll
        for (int n = 0; n < 4; n++)
            bfr[n] = *(const bf16x8*)&Blds[wn * 64 + n * 16 + l15][g * 8];
        #pragma unroll
        for (int m = 0; m < 4; m++)
            #pragma unroll
            for (int n = 0; n < 4; n++)
                acc[m][n] = mfma_bf16(af[m], bfr[n], acc[m][n]);
        __syncthreads();
    }

    #pragma unroll
    for (int m = 0; m < 4; m++) {
        const int grow0 = bm * 128 + wm * 64 + m * 16 + (g << 2);
        #pragma unroll
        for (int n = 0; n < 4; n++) {
            const int gcol = bn * 128 + wn * 64 + n * 16 + l15;
            const float bv2 = bias[gcol];
            f32x4 c = acc[m][n];
            #pragma unroll
            for (int r = 0; r < 4; r++)
                Out[(size_t)(grow0 + r) * 512 + gcol] = c[r] + bv2;
        }
    }
}

// ---------------------------------------------------------------------------
// Flash attention with multiplicative positional decay.
// Double-buffered K/V staged via global_load_lds with pre-swizzled source
// (linear LDS dest, XOR-swizzled read). One barrier per 64-key tile; next
// tile's loads fly under current tile's compute. Softmax in exp2 domain with
// defer-max (THR=4 log2 units) and lane-partial l accumulation.
// Grid: 1024 blocks = 16 (b,h) x 64 q-tiles of 64 rows; 4 waves x 16 q-rows.
// ---------------------------------------------------------------------------
__global__ __launch_bounds__(256, 4) void attn_decay(
    const unsigned short* __restrict__ Qh, const unsigned short* __restrict__ Kh,
    const unsigned short* __restrict__ Vt, const float* __restrict__ time_decay,
    const float* __restrict__ scale_p, unsigned short* __restrict__ ctx)
{
    __shared__ __align__(16) char Klds[2][8192];   // [buf][64 keys x 128B]
    __shared__ __align__(16) char Vlds[2][8192];   // [buf][64 d x 128B]
    __shared__ __align__(16) char Plds[4][2048];   // per-wave 16 rows x 128B

    const int tid  = threadIdx.x;
    const int lane = tid & 63;
    const int w    = tid >> 6;
    const int i    = blockIdx.x;
    // XCD swizzle (bijective, 1024 % 8 == 0): each XCD sees exactly 2 heads
    const int bh = ((i & 7) << 1) | ((i >> 9) & 1);
    const int qt = (i >> 3) & 63;
    const int h  = bh & 7;
    const int b  = bh >> 3;
    const int l15 = lane & 15;
    const int g   = lane >> 4;

    const float td    = time_decay[h];
    const float coefL = scale_p[0] * 0.125f * 1.44269504f;  // scale/sqrt(64)*log2(e)

    // Q fragments (16 rows x 64 d per wave)
    bf16x8 aq0, aq1;
    {
        const unsigned short* Qp = Qh + (((size_t)bh * 4096) + qt * 64 + w * 16 + l15) * 64 + g * 8;
        aq0 = *(const bf16x8*)Qp;
        aq1 = *(const bf16x8*)(Qp + 32);
    }

    f32x4 o[4];
    #pragma unroll
    for (int d = 0; d < 4; d++) o[d] = (f32x4){0.f, 0.f, 0.f, 0.f};
    float mrow[4]  = {-3e38f, -3e38f, -3e38f, -3e38f};  // log2-domain running max
    float lrowp[4] = {0.f, 0.f, 0.f, 0.f};              // lane-partial l

    // decay factor per key col (log2-scaled), advanced incrementally per tile
    float fac[4];
    #pragma unroll
    for (int n = 0; n < 4; n++)
        fac[n] = coefL * __expf(-td * (float)(n * 16 + l15));
    const float stepv = __expf(-td * 64.0f);

    // per-lane pre-swizzled staging source addresses (16B per lane per issue)
    const char* kg[2];
    const char* vg[2];
    int ldsoff[2];
    {
        const size_t kbaseB = (size_t)bh * 4096 * 64 * 2;
        const size_t vbaseB = (size_t)bh * 64 * 4096 * 2;
        #pragma unroll
        for (int j = 0; j < 2; j++) {
            const int p  = w * 2048 + j * 1024 + lane * 16;  // linear LDS byte pos
            const int r  = p >> 7, cc = p & 127;
            const int sw = (r & 7) << 4;
            kg[j] = (const char*)Kh + kbaseB + (size_t)r * 128  + (cc ^ sw);
            vg[j] = (const char*)Vt + vbaseB + (size_t)r * 8192 + (cc ^ sw);
            ldsoff[j] = w * 2048 + j * 1024;  // wave-uniform dest base
        }
    }

    // prologue: tile 0 -> buf 0
    #pragma unroll
    for (int j = 0; j < 2; j++) {
        gload16(kg[j], &Klds[0][ldsoff[j]]);
        gload16(vg[j], &Vlds[0][ldsoff[j]]);
    }

    int cur = 0;
    for (int kt = 0; kt < 64; ++kt) {
        __syncthreads();  // drains this tile's loads (vmcnt 0) + frees buf cur^1
        if (kt < 63) {
            const int nb = cur ^ 1;
            #pragma unroll
            for (int j = 0; j < 2; j++) {
                gload16(kg[j] + (size_t)(kt + 1) * 8192, &Klds[nb][ldsoff[j]]);
                gload16(vg[j] + (size_t)(kt + 1) * 128,  &Vlds[nb][ldsoff[j]]);
            }
        }
        const char* kb = Klds[cur];
        const char* vb = Vlds[cur];

        // ---- S = Q K^T (16 x 64 per wave) ----
        f32x4 s[4];
        __builtin_amdgcn_s_setprio(1);
        #pragma unroll
        for (int n = 0; n < 4; n++) {
            const int r  = n * 16 + l15;
            const int sw = (r & 7) << 4;
            bf16x8 k0 = *(const bf16x8*)(kb + r * 128 + ((g * 16) ^ sw));
            bf16x8 k1 = *(const bf16x8*)(kb + r * 128 + ((64 + g * 16) ^ sw));
            f32x4 z = (f32x4){0.f, 0.f, 0.f, 0.f};
            z = mfma_bf16(aq0, k0, z);
            z = mfma_bf16(aq1, k1, z);
            s[n] = z;
        }
        __builtin_amdgcn_s_setprio(0);

        // ---- decayed scores (log2 domain) + defer-max online softmax ----
        float sv[4][4];
        float inmax[4] = {-3e38f, -3e38f, -3e38f, -3e38f};
        #pragma unroll
        for (int n = 0; n < 4; n++)
            #pragma unroll
            for (int r = 0; r < 4; r++) {
                float x = s[n][r] * fac[n];
                sv[n][r] = x;
                inmax[r] = fmaxf(inmax[r], x);
            }
        float exc = fmaxf(fmaxf(inmax[0] - mrow[0], inmax[1] - mrow[1]),
                          fmaxf(inmax[2] - mrow[2], inmax[3] - mrow[3]));
        if (__any(exc > 4.0f)) {
            // slow path (fires ~only on first tile): full row-max + rescale
            #pragma unroll
            for (int r = 0; r < 4; r++) {
                float t = inmax[r];
                t = fmaxf(t, __shfl_xor(t, 1));
                t = fmaxf(t, __shfl_xor(t, 2));
                t = fmaxf(t, __shfl_xor(t, 4));
                t = fmaxf(t, __shfl_xor(t, 8));
                float mnew = fmaxf(mrow[r], t);
                float a = __builtin_amdgcn_exp2f(mrow[r] - mnew);
                mrow[r] = mnew;
                lrowp[r] *= a;
                #pragma unroll
                for (int d = 0; d < 4; d++) o[d][r] *= a;
            }
        }
        unsigned short pb[4][4];
        #pragma unroll
        for (int n = 0; n < 4; n++)
            #pragma unroll
            for (int r = 0; r < 4; r++) {
                float p = __builtin_amdgcn_exp2f(sv[n][r] - mrow[r]);  // <= 2^4
                lrowp[r] += p;
                pb[n][r] = bfbits(p);
            }
        #pragma unroll
        for (int n = 0; n < 4; n++) fac[n] *= stepv;

        // ---- P -> per-wave LDS (swizzled), then PV ----
        char* pw = Plds[w];
        #pragma unroll
        for (int r = 0; r < 4; r++) {
            const int row = g * 4 + r;
            const int sw  = (row & 7) << 4;
            #pragma unroll
            for (int n = 0; n < 4; n++) {
                const int cb = (n * 16 + l15) * 2;
                *(unsigned short*)(pw + row * 128 + (cb ^ sw)) = pb[n][r];
            }
        }
        {
            const int row = l15;
            const int sw  = (row & 7) << 4;
            bf16x8 pa0 = *(const bf16x8*)(pw + row * 128 + ((g * 16) ^ sw));
            bf16x8 pa1 = *(const bf16x8*)(pw + row * 128 + ((64 + g * 16) ^ sw));
            __builtin_amdgcn_s_setprio(1);
            #pragma unroll
            for (int d = 0; d < 4; d++) {
                const int vr  = d * 16 + l15;
                const int vsw = (vr & 7) << 4;
                bf16x8 v0 = *(const bf16x8*)(vb + vr * 128 + ((g * 16) ^ vsw));
                bf16x8 v1 = *(const bf16x8*)(vb + vr * 128 + ((64 + g * 16) ^ vsw));
                o[d] = mfma_bf16(pa0, v0, o[d]);
                o[d] = mfma_bf16(pa1, v1, o[d]);
            }
            __builtin_amdgcn_s_setprio(0);
        }
        cur ^= 1;
    }

    // ---- reduce l across the 16-lane row groups, normalize, write ----
    float inv[4];
    #pragma unroll
    for (int r = 0; r < 4; r++) {
        float t = lrowp[r];
        t += __shfl_xor(t, 1);
        t += __shfl_xor(t, 2);
        t += __shfl_xor(t, 4);
        t += __shfl_xor(t, 8);
        inv[r] = 1.f / t;
    }
    #pragma unroll
    for (int d = 0; d < 4; d++)
        #pragma unroll
        for (int r = 0; r < 4; r++) {
            const int srow_ = qt * 64 + w * 16 + g * 4 + r;
            const size_t idx = ((size_t)b * 4096 + srow_) * 512 + h * 64 + d * 16 + l15;
            ctx[idx] = bfbits(o[d][r] * inv[r]);
        }
}

// ---------------------------------------------------------------------------
extern "C" void kernel_launch(void* const* d_in, const int* in_sizes, int n_in,
                              void* d_out, int out_size, void* d_ws, size_t ws_size,
                              hipStream_t stream)
{
    (void)in_sizes; (void)n_in; (void)out_size; (void)ws_size;
    const float* q  = (const float*)d_in[0];
    const float* k  = (const float*)d_in[1];
    const float* v  = (const float*)d_in[2];
    const float* Wq = (const float*)d_in[3];
    const float* bq = (const float*)d_in[4];
    const float* Wk = (const float*)d_in[5];
    const float* bk = (const float*)d_in[6];
    const float* Wv = (const float*)d_in[7];
    const float* bv = (const float*)d_in[8];
    const float* Wo = (const float*)d_in[9];
    const float* bo = (const float*)d_in[10];
    const float* td = (const float*)d_in[11];
    const float* sc = (const float*)d_in[12];

    // workspace: Qh, Kh, Vt, ctx — 8 MB each (bf16), 32 MB total
    unsigned short* Qh  = (unsigned short*)d_ws;
    unsigned short* Kh  = Qh + (size_t)16 * 4096 * 64;
    unsigned short* Vt  = Kh + (size_t)16 * 4096 * 64;
    unsigned short* ctx = Vt + (size_t)16 * 4096 * 64;

    gemm_qkv<<<dim3(4, 64, 3), 256, 0, stream>>>(q, k, v, Wq, bq, Wk, bk, Wv, bv, Qh, Kh, Vt);
    attn_decay<<<dim3(1024), 256, 0, stream>>>(Qh, Kh, Vt, td, sc, ctx);
    gemm_out<<<dim3(4, 64), 256, 0, stream>>>(ctx, Wo, bo, (float*)d_out);
}

// Round 4
// 165.539 us; speedup vs baseline: 2.0266x; 1.1281x over previous
//
#include <hip/hip_runtime.h>
#include <hip/hip_bf16.h>
#include <stdint.h>

typedef __attribute__((ext_vector_type(8))) __bf16 bf16x8;
typedef __attribute__((ext_vector_type(4))) float f32x4;
typedef __attribute__((ext_vector_type(16))) float f32x16;
typedef __attribute__((ext_vector_type(8))) unsigned short ushort8;
typedef __attribute__((ext_vector_type(4))) unsigned short ushort4v;
typedef __attribute__((ext_vector_type(2))) unsigned int uint2v;
typedef __attribute__((ext_vector_type(4))) unsigned int uint4v;

__device__ __forceinline__ unsigned short bfbits(float x) {
    __bf16 b = (__bf16)x;
    return __builtin_bit_cast(unsigned short, b);
}

__device__ __forceinline__ f32x4 mfma16(bf16x8 a, bf16x8 b, f32x4 c) {
    return __builtin_amdgcn_mfma_f32_16x16x32_bf16(a, b, c, 0, 0, 0);
}
__device__ __forceinline__ f32x16 mfma32(bf16x8 a, bf16x8 b, f32x16 c) {
    return __builtin_amdgcn_mfma_f32_32x32x16_bf16(a, b, c, 0, 0, 0);
}

__device__ __forceinline__ unsigned int cvtpk(float lo, float hi) {
    unsigned int r;
    asm("v_cvt_pk_bf16_f32 %0, %1, %2" : "=v"(r) : "v"(lo), "v"(hi));
    return r;
}

// cross-lane pull: value of `src` at lane `srcl` (in-register, race-free)
__device__ __forceinline__ float lanepull(float src, int srcl) {
    return __builtin_bit_cast(float,
        __builtin_amdgcn_ds_bpermute(srcl * 4, __builtin_bit_cast(int, src)));
}

__device__ __forceinline__ void gload16(const void* g, void* l) {
    __builtin_amdgcn_global_load_lds(
        (const __attribute__((address_space(1))) unsigned int*)g,
        (__attribute__((address_space(3))) unsigned int*)l, 16, 0, 0);
}

__device__ __forceinline__ f32x16 zero16() {
    f32x16 r;
    #pragma unroll
    for (int i = 0; i < 16; i++) r[i] = 0.f;
    return r;
}

// ---------------------------------------------------------------------------
// Merged Q/K/V projection GEMM. z=0: Qh (scaled by scale/8*log2e),
// z=1: Kh (row s scaled by exp(-td_h*s)), z=2: Vt transposed.
// ---------------------------------------------------------------------------
__global__ __launch_bounds__(256) void gemm_qkv(
    const float* __restrict__ q, const float* __restrict__ k, const float* __restrict__ v,
    const float* __restrict__ Wq, const float* __restrict__ bq,
    const float* __restrict__ Wk, const float* __restrict__ bk,
    const float* __restrict__ Wv, const float* __restrict__ bv,
    const float* __restrict__ td, const float* __restrict__ sc,
    unsigned short* __restrict__ Qh, unsigned short* __restrict__ Kh,
    unsigned short* __restrict__ Vt)
{
    __shared__ unsigned short Alds[128][40];
    __shared__ unsigned short Blds[128][40];

    const int z = blockIdx.z;
    const float* A0   = (z == 0) ? q  : (z == 1) ? k  : v;
    const float* W    = (z == 0) ? Wq : (z == 1) ? Wk : Wv;
    const float* bias = (z == 0) ? bq : (z == 1) ? bk : bv;

    const int tid  = threadIdx.x;
    const int lane = tid & 63;
    const int wid  = tid >> 6;
    const int wm   = wid >> 1, wn = wid & 1;
    const int bm   = blockIdx.y, bn = blockIdx.x;
    const int l15  = lane & 15;
    const int g    = lane >> 4;
    const int srow = tid >> 1;
    const int scol = (tid & 1) * 16;

    f32x4 acc[4][4];
    #pragma unroll
    for (int m = 0; m < 4; m++)
        #pragma unroll
        for (int n = 0; n < 4; n++)
            acc[m][n] = (f32x4){0.f, 0.f, 0.f, 0.f};

    for (int k0 = 0; k0 < 512; k0 += 32) {
        {
            const float* A = A0 + (size_t)(bm * 128 + srow) * 512 + k0 + scol;
            float4 v0 = ((const float4*)A)[0];
            float4 v1 = ((const float4*)A)[1];
            float4 v2 = ((const float4*)A)[2];
            float4 v3 = ((const float4*)A)[3];
            ushort8 p0 = { bfbits(v0.x), bfbits(v0.y), bfbits(v0.z), bfbits(v0.w),
                           bfbits(v1.x), bfbits(v1.y), bfbits(v1.z), bfbits(v1.w) };
            ushort8 p1 = { bfbits(v2.x), bfbits(v2.y), bfbits(v2.z), bfbits(v2.w),
                           bfbits(v3.x), bfbits(v3.y), bfbits(v3.z), bfbits(v3.w) };
            *(ushort8*)&Alds[srow][scol]     = p0;
            *(ushort8*)&Alds[srow][scol + 8] = p1;
        }
        {
            const float* Bp = W + (size_t)(bn * 128 + srow) * 512 + k0 + scol;
            float4 v0 = ((const float4*)Bp)[0];
            float4 v1 = ((const float4*)Bp)[1];
            float4 v2 = ((const float4*)Bp)[2];
            float4 v3 = ((const float4*)Bp)[3];
            ushort8 p0 = { bfbits(v0.x), bfbits(v0.y), bfbits(v0.z), bfbits(v0.w),
                           bfbits(v1.x), bfbits(v1.y), bfbits(v1.z), bfbits(v1.w) };
            ushort8 p1 = { bfbits(v2.x), bfbits(v2.y), bfbits(v2.z), bfbits(v2.w),
                           bfbits(v3.x), bfbits(v3.y), bfbits(v3.z), bfbits(v3.w) };
            *(ushort8*)&Blds[srow][scol]     = p0;
            *(ushort8*)&Blds[srow][scol + 8] = p1;
        }
        __syncthreads();

        bf16x8 af[4], bfr[4];
        #pragma unroll
        for (int m = 0; m < 4; m++)
            af[m] = *(const bf16x8*)&Alds[wm * 64 + m * 16 + l15][g * 8];
        #pragma unroll
        for (int n = 0; n < 4; n++)
            bfr[n] = *(const bf16x8*)&Blds[wn * 64 + n * 16 + l15][g * 8];
        #pragma unroll
        for (int m = 0; m < 4; m++)
            #pragma unroll
            for (int n = 0; n < 4; n++)
                acc[m][n] = mfma16(af[m], bfr[n], acc[m][n]);
        __syncthreads();
    }

    const float coefL = sc[0] * 0.125f * 1.44269504f;

    #pragma unroll
    for (int m = 0; m < 4; m++) {
        const int grow0 = bm * 128 + wm * 64 + m * 16 + (g << 2);
        #pragma unroll
        for (int n = 0; n < 4; n++) {
            const int gcol = bn * 128 + wn * 64 + n * 16 + l15;
            const float bv2 = bias[gcol];
            f32x4 c = acc[m][n];
            const int b = grow0 >> 12, s0 = grow0 & 4095;
            const int h = gcol >> 6, dk = gcol & 63;
            if (z == 0) {
                const size_t base = ((size_t)(b * 8 + h) * 4096 + s0) * 64 + dk;
                #pragma unroll
                for (int r = 0; r < 4; r++)
                    Qh[base + (size_t)r * 64] = bfbits((c[r] + bv2) * coefL);
            } else if (z == 1) {
                const float tdh = td[h];
                const size_t base = ((size_t)(b * 8 + h) * 4096 + s0) * 64 + dk;
                #pragma unroll
                for (int r = 0; r < 4; r++)
                    Kh[base + (size_t)r * 64] = bfbits((c[r] + bv2) * __expf(-tdh * (float)(s0 + r)));
            } else {
                ushort4v pk = { bfbits(c[0] + bv2), bfbits(c[1] + bv2),
                                bfbits(c[2] + bv2), bfbits(c[3] + bv2) };
                *(ushort4v*)&Vt[((size_t)(b * 8 + h) * 64 + dk) * 4096 + s0] = pk;
            }
        }
    }
}

// ---------------------------------------------------------------------------
// Output projection GEMM: A = ctx bf16 [8192][512], out fp32.
// ---------------------------------------------------------------------------
__global__ __launch_bounds__(256) void gemm_out(
    const unsigned short* __restrict__ Actx, const float* __restrict__ W,
    const float* __restrict__ bias, float* __restrict__ Out)
{
    __shared__ unsigned short Alds[128][40];
    __shared__ unsigned short Blds[128][40];

    const int tid  = threadIdx.x;
    const int lane = tid & 63;
    const int wid  = tid >> 6;
    const int wm   = wid >> 1, wn = wid & 1;
    const int bm   = blockIdx.y, bn = blockIdx.x;
    const int l15  = lane & 15;
    const int g    = lane >> 4;
    const int srow = tid >> 1;
    const int scol = (tid & 1) * 16;

    f32x4 acc[4][4];
    #pragma unroll
    for (int m = 0; m < 4; m++)
        #pragma unroll
        for (int n = 0; n < 4; n++)
            acc[m][n] = (f32x4){0.f, 0.f, 0.f, 0.f};

    for (int k0 = 0; k0 < 512; k0 += 32) {
        {
            const unsigned short* A = Actx + (size_t)(bm * 128 + srow) * 512 + k0 + scol;
            ushort8 p0 = ((const ushort8*)A)[0];
            ushort8 p1 = ((const ushort8*)A)[1];
            *(ushort8*)&Alds[srow][scol]     = p0;
            *(ushort8*)&Alds[srow][scol + 8] = p1;
        }
        {
            const float* Bp = W + (size_t)(bn * 128 + srow) * 512 + k0 + scol;
            float4 v0 = ((const float4*)Bp)[0];
            float4 v1 = ((const float4*)Bp)[1];
            float4 v2 = ((const float4*)Bp)[2];
            float4 v3 = ((const float4*)Bp)[3];
            ushort8 p0 = { bfbits(v0.x), bfbits(v0.y), bfbits(v0.z), bfbits(v0.w),
                           bfbits(v1.x), bfbits(v1.y), bfbits(v1.z), bfbits(v1.w) };
            ushort8 p1 = { bfbits(v2.x), bfbits(v2.y), bfbits(v2.z), bfbits(v2.w),
                           bfbits(v3.x), bfbits(v3.y), bfbits(v3.z), bfbits(v3.w) };
            *(ushort8*)&Blds[srow][scol]     = p0;
            *(ushort8*)&Blds[srow][scol + 8] = p1;
        }
        __syncthreads();

        bf16x8 af[4], bfr[4];
        #pragma unroll
        for (int m = 0; m < 4; m++)
            af[m] = *(const bf16x8*)&Alds[wm * 64 + m * 16 + l15][g * 8];
        #pragma unroll
        for (int n = 0; n < 4; n++)
            bfr[n] = *(const bf16x8*)&Blds[wn * 64 + n * 16 + l15][g * 8];
        #pragma unroll
        for (int m = 0; m < 4; m++)
            #pragma unroll
            for (int n = 0; n < 4; n++)
                acc[m][n] = mfma16(af[m], bfr[n], acc[m][n]);
        __syncthreads();
    }

    #pragma unroll
    for (int m = 0; m < 4; m++) {
        const int grow0 = bm * 128 + wm * 64 + m * 16 + (g << 2);
        #pragma unroll
        for (int n = 0; n < 4; n++) {
            const int gcol = bn * 128 + wn * 64 + n * 16 + l15;
            const float bv2 = bias[gcol];
            f32x4 c = acc[m][n];
            #pragma unroll
            for (int r = 0; r < 4; r++)
                Out[(size_t)(grow0 + r) * 512 + gcol] = c[r] + bv2;
        }
    }
}

// ---------------------------------------------------------------------------
// Flash attention, swapped 32x32x16 QK^T, in-register softmax (decay/scale
// pre-folded into Qh/Kh), P->bf16 via cvt_pk + permlane32_swap, 32x32x16 PV.
// All cross-lane redistribution via ds_bpermute (in-register, race-free);
// cross-wave merge barrier-separated at every LDS phase.
// Grid: 1024 blocks (16 bh x 64 q-tiles), 4 waves = 2 qg x 2 key-halves.
// ---------------------------------------------------------------------------
__global__ __launch_bounds__(256, 4) void attn_decay(
    const unsigned short* __restrict__ Qh, const unsigned short* __restrict__ Kh,
    const unsigned short* __restrict__ Vt, unsigned short* __restrict__ ctx)
{
    // [0,16K): K dbuf | [16K,32K): V dbuf
    // epilogue reuse: Oscr[qg][32][64] f32 at [0,16K); m/l scratch at [16K,+1K)
    __shared__ __align__(16) char LDSB[32768];

    const int tid  = threadIdx.x;
    const int lane = tid & 63;
    const int w    = tid >> 6;
    const int qg   = w >> 1;      // q sub-tile (0..1)
    const int ws   = w & 1;       // key half (0..1)
    const int l31  = lane & 31;
    const int hl   = lane >> 5;

    const int i  = blockIdx.x;
    const int bh = ((i & 7) << 1) | ((i >> 9) & 1);  // XCD swizzle, bijective
    const int qt = (i >> 3) & 63;
    const int h  = bh & 7;
    const int b  = bh >> 3;

    // Q fragments: B-operand, 4 dk-chunks (Qh already scaled by coef*log2e)
    bf16x8 qf[4];
    {
        const unsigned short* Qp =
            Qh + ((size_t)bh * 4096 + qt * 64 + qg * 32 + l31) * 64 + hl * 8;
        #pragma unroll
        for (int c = 0; c < 4; c++)
            qf[c] = *(const bf16x8*)(Qp + c * 16);
    }

    f32x16 o0 = zero16(), o1 = zero16();   // d 0-31 / 32-63
    float m = -3e38f, lp = 0.f;

    // staging: per-wave pre-swizzled global sources, linear LDS dest
    const char* kg[2];
    const char* vg[2];
    int ldsoff[2];
    {
        const size_t kbaseB = (size_t)bh * 4096 * 64 * 2;
        const size_t vbaseB = (size_t)bh * 64 * 4096 * 2;
        #pragma unroll
        for (int j = 0; j < 2; j++) {
            const int p  = w * 2048 + j * 1024 + lane * 16;
            const int r  = p >> 7, cc = p & 127;
            const int sw = (r & 7) << 4;
            kg[j] = (const char*)Kh + kbaseB + (size_t)r * 128  + (cc ^ sw);
            vg[j] = (const char*)Vt + vbaseB + (size_t)r * 8192 + (cc ^ sw);
            ldsoff[j] = w * 2048 + j * 1024;
        }
    }
    #pragma unroll
    for (int j = 0; j < 2; j++) {
        gload16(kg[j], LDSB + ldsoff[j]);
        gload16(vg[j], LDSB + 16384 + ldsoff[j]);
    }

    const int krow = ws * 32 + l31;
    const int ksw  = (krow & 7) << 4;

    int cur = 0;
    for (int kt = 0; kt < 64; ++kt) {
        asm volatile("s_waitcnt vmcnt(0)" ::: "memory");  // own loads drained
        __syncthreads();  // tile `cur` ready for all waves
        if (kt < 63) {
            const int nb = cur ^ 1;
            #pragma unroll
            for (int j = 0; j < 2; j++) {
                gload16(kg[j] + (size_t)(kt + 1) * 8192, LDSB + nb * 8192 + ldsoff[j]);
                gload16(vg[j] + (size_t)(kt + 1) * 128,  LDSB + 16384 + nb * 8192 + ldsoff[j]);
            }
        }
        const char* kb = LDSB + cur * 8192;
        const char* vb = LDSB + 16384 + cur * 8192;

        // ---- S^T = K Q^T : 32 keys (this wave's half) x 32 q-rows ----
        f32x16 s = zero16();
        __builtin_amdgcn_s_setprio(1);
        #pragma unroll
        for (int c = 0; c < 4; c++) {
            bf16x8 kf = *(const bf16x8*)(kb + krow * 128 + ((c * 32 + hl * 16) ^ ksw));
            s = mfma32(kf, qf[c], s);
        }
        __builtin_amdgcn_s_setprio(0);

        // ---- online softmax (log2 domain), defer-max THR=4 ----
        float x01 = fmaxf(fmaxf(s[0], s[1]),   fmaxf(s[2], s[3]));
        float x23 = fmaxf(fmaxf(s[4], s[5]),   fmaxf(s[6], s[7]));
        float x45 = fmaxf(fmaxf(s[8], s[9]),   fmaxf(s[10], s[11]));
        float x67 = fmaxf(fmaxf(s[12], s[13]), fmaxf(s[14], s[15]));
        float inmax = fmaxf(fmaxf(x01, x23), fmaxf(x45, x67));
        if (__any(inmax - m > 4.0f)) {
            // slow path (rare): full row-max + rescale; alpha redistributed
            // lane->reg via ds_bpermute (no LDS, no ordering hazards)
            float t  = fmaxf(inmax, __shfl_xor(inmax, 32));
            float mn = fmaxf(m, t);
            float al = __builtin_amdgcn_exp2f(m - mn);
            m = mn;
            lp *= al;
            #pragma unroll
            for (int rc = 0; rc < 4; rc++)
                #pragma unroll
                for (int j = 0; j < 4; j++) {
                    const float a = lanepull(al, rc * 8 + hl * 4 + j);
                    o0[rc * 4 + j] *= a;
                    o1[rc * 4 + j] *= a;
                }
        }
        float p[16];
        #pragma unroll
        for (int r = 0; r < 16; r++) {
            p[r] = __builtin_amdgcn_exp2f(s[r] - m);
            lp += p[r];
        }

        // ---- pack P to bf16 fragments (cvt_pk + permlane32_swap) ----
        unsigned int W0 = cvtpk(p[0], p[1]),   W1 = cvtpk(p[2], p[3]);
        unsigned int W2 = cvtpk(p[4], p[5]),   W3 = cvtpk(p[6], p[7]);
        unsigned int W4 = cvtpk(p[8], p[9]),   W5 = cvtpk(p[10], p[11]);
        unsigned int W6 = cvtpk(p[12], p[13]), W7 = cvtpk(p[14], p[15]);
        uint2v r02 = __builtin_amdgcn_permlane32_swap(W0, W2, false, false);
        uint2v r13 = __builtin_amdgcn_permlane32_swap(W1, W3, false, false);
        uint2v r46 = __builtin_amdgcn_permlane32_swap(W4, W6, false, false);
        uint2v r57 = __builtin_amdgcn_permlane32_swap(W5, W7, false, false);
        bf16x8 pa0 = __builtin_bit_cast(bf16x8, (uint4v){r02.x, r13.x, r02.y, r13.y});
        bf16x8 pa1 = __builtin_bit_cast(bf16x8, (uint4v){r46.x, r57.x, r46.y, r57.y});

        // ---- PV: O[32q][64d] += P[32q][32k] V[32k][64d] ----
        __builtin_amdgcn_s_setprio(1);
        #pragma unroll
        for (int dt = 0; dt < 2; dt++) {
            const int vr  = dt * 32 + l31;
            const int vsw = (vr & 7) << 4;
            bf16x8 vf0 = *(const bf16x8*)(vb + vr * 128 + ((ws * 64 + hl * 16) ^ vsw));
            bf16x8 vf1 = *(const bf16x8*)(vb + vr * 128 + ((ws * 64 + 32 + hl * 16) ^ vsw));
            if (dt == 0) { o0 = mfma32(pa0, vf0, o0); o0 = mfma32(pa1, vf1, o0); }
            else         { o1 = mfma32(pa0, vf0, o1); o1 = mfma32(pa1, vf1, o1); }
        }
        __builtin_amdgcn_s_setprio(0);
        cur ^= 1;
    }

    // ---- split-K merge across ws pair (barrier-separated LDS phases) ----
    float lw = lp + __shfl_xor(lp, 32);   // total l for q=l31 over wave's 32 keys
    __syncthreads();                      // (1) all loop LDS reads done
    float* mscr = (float*)(LDSB + 16384);
    float* lscr = (float*)(LDSB + 16896);
    if (lane < 32) {
        mscr[(qg * 2 + ws) * 32 + lane] = m;
        lscr[(qg * 2 + ws) * 32 + lane] = lw;
    }
    __syncthreads();                      // (2) m/l published
    const float pm  = mscr[(qg * 2 + (ws ^ 1)) * 32 + l31];
    const float pl2 = lscr[(qg * 2 + (ws ^ 1)) * 32 + l31];
    const float msr   = fmaxf(m, pm);
    const float beta  = __builtin_amdgcn_exp2f(m - msr);
    const float pbeta = __builtin_amdgcn_exp2f(pm - msr);
    const float myscale = beta / (beta * lw + pbeta * pl2);
    #pragma unroll
    for (int rc = 0; rc < 4; rc++)
        #pragma unroll
        for (int j = 0; j < 4; j++) {
            const float a = lanepull(myscale, rc * 8 + hl * 4 + j);
            o0[rc * 4 + j] *= a;
            o1[rc * 4 + j] *= a;
        }
    __syncthreads();                      // (3) scratch reads done; reuse [0,16K)
    float* Oscr = (float*)(LDSB + qg * 8192);   // [32][64]
    if (ws == 1) {
        #pragma unroll
        for (int reg = 0; reg < 16; reg++) {
            const int row = (reg & 3) + 8 * (reg >> 2) + 4 * hl;
            Oscr[row * 64 + l31]      = o0[reg];
            Oscr[row * 64 + 32 + l31] = o1[reg];
        }
    }
    __syncthreads();                      // (4) O-halves published
    if (ws == 0) {
        #pragma unroll
        for (int reg = 0; reg < 16; reg++) {
            const int row = (reg & 3) + 8 * (reg >> 2) + 4 * hl;
            const float v0 = o0[reg] + Oscr[row * 64 + l31];
            const float v1 = o1[reg] + Oscr[row * 64 + 32 + l31];
            const int srow_ = qt * 64 + qg * 32 + row;
            const size_t idx = ((size_t)b * 4096 + srow_) * 512 + h * 64;
            ctx[idx + l31]      = bfbits(v0);
            ctx[idx + 32 + l31] = bfbits(v1);
        }
    }
}

// ---------------------------------------------------------------------------
extern "C" void kernel_launch(void* const* d_in, const int* in_sizes, int n_in,
                              void* d_out, int out_size, void* d_ws, size_t ws_size,
                              hipStream_t stream)
{
    (void)in_sizes; (void)n_in; (void)out_size; (void)ws_size;
    const float* q  = (const float*)d_in[0];
    const float* k  = (const float*)d_in[1];
    const float* v  = (const float*)d_in[2];
    const float* Wq = (const float*)d_in[3];
    const float* bq = (const float*)d_in[4];
    const float* Wk = (const float*)d_in[5];
    const float* bk = (const float*)d_in[6];
    const float* Wv = (const float*)d_in[7];
    const float* bv = (const float*)d_in[8];
    const float* Wo = (const float*)d_in[9];
    const float* bo = (const float*)d_in[10];
    const float* td = (const float*)d_in[11];
    const float* sc = (const float*)d_in[12];

    unsigned short* Qh  = (unsigned short*)d_ws;
    unsigned short* Kh  = Qh + (size_t)16 * 4096 * 64;
    unsigned short* Vt  = Kh + (size_t)16 * 4096 * 64;
    unsigned short* ctx = Vt + (size_t)16 * 4096 * 64;

    gemm_qkv<<<dim3(4, 64, 3), 256, 0, stream>>>(q, k, v, Wq, bq, Wk, bk, Wv, bv, td, sc, Qh, Kh, Vt);
    attn_decay<<<dim3(1024), 256, 0, stream>>>(Qh, Kh, Vt, ctx);
    gemm_out<<<dim3(4, 64), 256, 0, stream>>>(ctx, Wo, bo, (float*)d_out);
}

// Round 5
// 148.679 us; speedup vs baseline: 2.2564x; 1.1134x over previous
//
#include <hip/hip_runtime.h>
#include <hip/hip_bf16.h>
#include <stdint.h>

typedef __attribute__((ext_vector_type(8))) __bf16 bf16x8;
typedef __attribute__((ext_vector_type(4))) float f32x4;
typedef __attribute__((ext_vector_type(16))) float f32x16;
typedef __attribute__((ext_vector_type(8))) unsigned short ushort8;
typedef __attribute__((ext_vector_type(4))) unsigned short ushort4v;
typedef __attribute__((ext_vector_type(2))) unsigned int uint2v;
typedef __attribute__((ext_vector_type(4))) unsigned int uint4v;

__device__ __forceinline__ unsigned short bfbits(float x) {
    __bf16 b = (__bf16)x;
    return __builtin_bit_cast(unsigned short, b);
}

__device__ __forceinline__ f32x4 mfma16(bf16x8 a, bf16x8 b, f32x4 c) {
    return __builtin_amdgcn_mfma_f32_16x16x32_bf16(a, b, c, 0, 0, 0);
}
__device__ __forceinline__ f32x16 mfma32(bf16x8 a, bf16x8 b, f32x16 c) {
    return __builtin_amdgcn_mfma_f32_32x32x16_bf16(a, b, c, 0, 0, 0);
}

__device__ __forceinline__ unsigned int cvtpk(float lo, float hi) {
    unsigned int r;
    asm("v_cvt_pk_bf16_f32 %0, %1, %2" : "=v"(r) : "v"(lo), "v"(hi));
    return r;
}

// cross-lane pull: value of `src` at lane `srcl` (in-register, race-free)
__device__ __forceinline__ float lanepull(float src, int srcl) {
    return __builtin_bit_cast(float,
        __builtin_amdgcn_ds_bpermute(srcl * 4, __builtin_bit_cast(int, src)));
}

__device__ __forceinline__ void gload16(const void* g, void* l) {
    __builtin_amdgcn_global_load_lds(
        (const __attribute__((address_space(1))) unsigned int*)g,
        (__attribute__((address_space(3))) unsigned int*)l, 16, 0, 0);
}

__device__ __forceinline__ f32x16 zero16() {
    f32x16 r;
    #pragma unroll
    for (int i = 0; i < 16; i++) r[i] = 0.f;
    return r;
}

// ---------------------------------------------------------------------------
// Merged Q/K/V projection GEMM. z=0: Qh (scaled by scale/8*log2e),
// z=1: Kh (row s scaled by exp(-td_h*s)), z=2: Vt transposed.
// ---------------------------------------------------------------------------
__global__ __launch_bounds__(256) void gemm_qkv(
    const float* __restrict__ q, const float* __restrict__ k, const float* __restrict__ v,
    const float* __restrict__ Wq, const float* __restrict__ bq,
    const float* __restrict__ Wk, const float* __restrict__ bk,
    const float* __restrict__ Wv, const float* __restrict__ bv,
    const float* __restrict__ td, const float* __restrict__ sc,
    unsigned short* __restrict__ Qh, unsigned short* __restrict__ Kh,
    unsigned short* __restrict__ Vt)
{
    __shared__ unsigned short Alds[128][40];
    __shared__ unsigned short Blds[128][40];

    const int z = blockIdx.z;
    const float* A0   = (z == 0) ? q  : (z == 1) ? k  : v;
    const float* W    = (z == 0) ? Wq : (z == 1) ? Wk : Wv;
    const float* bias = (z == 0) ? bq : (z == 1) ? bk : bv;

    const int tid  = threadIdx.x;
    const int lane = tid & 63;
    const int wid  = tid >> 6;
    const int wm   = wid >> 1, wn = wid & 1;
    const int bm   = blockIdx.y, bn = blockIdx.x;
    const int l15  = lane & 15;
    const int g    = lane >> 4;
    const int srow = tid >> 1;
    const int scol = (tid & 1) * 16;

    f32x4 acc[4][4];
    #pragma unroll
    for (int m = 0; m < 4; m++)
        #pragma unroll
        for (int n = 0; n < 4; n++)
            acc[m][n] = (f32x4){0.f, 0.f, 0.f, 0.f};

    for (int k0 = 0; k0 < 512; k0 += 32) {
        {
            const float* A = A0 + (size_t)(bm * 128 + srow) * 512 + k0 + scol;
            float4 v0 = ((const float4*)A)[0];
            float4 v1 = ((const float4*)A)[1];
            float4 v2 = ((const float4*)A)[2];
            float4 v3 = ((const float4*)A)[3];
            ushort8 p0 = { bfbits(v0.x), bfbits(v0.y), bfbits(v0.z), bfbits(v0.w),
                           bfbits(v1.x), bfbits(v1.y), bfbits(v1.z), bfbits(v1.w) };
            ushort8 p1 = { bfbits(v2.x), bfbits(v2.y), bfbits(v2.z), bfbits(v2.w),
                           bfbits(v3.x), bfbits(v3.y), bfbits(v3.z), bfbits(v3.w) };
            *(ushort8*)&Alds[srow][scol]     = p0;
            *(ushort8*)&Alds[srow][scol + 8] = p1;
        }
        {
            const float* Bp = W + (size_t)(bn * 128 + srow) * 512 + k0 + scol;
            float4 v0 = ((const float4*)Bp)[0];
            float4 v1 = ((const float4*)Bp)[1];
            float4 v2 = ((const float4*)Bp)[2];
            float4 v3 = ((const float4*)Bp)[3];
            ushort8 p0 = { bfbits(v0.x), bfbits(v0.y), bfbits(v0.z), bfbits(v0.w),
                           bfbits(v1.x), bfbits(v1.y), bfbits(v1.z), bfbits(v1.w) };
            ushort8 p1 = { bfbits(v2.x), bfbits(v2.y), bfbits(v2.z), bfbits(v2.w),
                           bfbits(v3.x), bfbits(v3.y), bfbits(v3.z), bfbits(v3.w) };
            *(ushort8*)&Blds[srow][scol]     = p0;
            *(ushort8*)&Blds[srow][scol + 8] = p1;
        }
        __syncthreads();

        bf16x8 af[4], bfr[4];
        #pragma unroll
        for (int m = 0; m < 4; m++)
            af[m] = *(const bf16x8*)&Alds[wm * 64 + m * 16 + l15][g * 8];
        #pragma unroll
        for (int n = 0; n < 4; n++)
            bfr[n] = *(const bf16x8*)&Blds[wn * 64 + n * 16 + l15][g * 8];
        #pragma unroll
        for (int m = 0; m < 4; m++)
            #pragma unroll
            for (int n = 0; n < 4; n++)
                acc[m][n] = mfma16(af[m], bfr[n], acc[m][n]);
        __syncthreads();
    }

    const float coefL = sc[0] * 0.125f * 1.44269504f;

    #pragma unroll
    for (int m = 0; m < 4; m++) {
        const int grow0 = bm * 128 + wm * 64 + m * 16 + (g << 2);
        #pragma unroll
        for (int n = 0; n < 4; n++) {
            const int gcol = bn * 128 + wn * 64 + n * 16 + l15;
            const float bv2 = bias[gcol];
            f32x4 c = acc[m][n];
            const int b = grow0 >> 12, s0 = grow0 & 4095;
            const int h = gcol >> 6, dk = gcol & 63;
            if (z == 0) {
                const size_t base = ((size_t)(b * 8 + h) * 4096 + s0) * 64 + dk;
                #pragma unroll
                for (int r = 0; r < 4; r++)
                    Qh[base + (size_t)r * 64] = bfbits((c[r] + bv2) * coefL);
            } else if (z == 1) {
                const float tdh = td[h];
                const size_t base = ((size_t)(b * 8 + h) * 4096 + s0) * 64 + dk;
                #pragma unroll
                for (int r = 0; r < 4; r++)
                    Kh[base + (size_t)r * 64] = bfbits((c[r] + bv2) * __expf(-tdh * (float)(s0 + r)));
            } else {
                ushort4v pk = { bfbits(c[0] + bv2), bfbits(c[1] + bv2),
                                bfbits(c[2] + bv2), bfbits(c[3] + bv2) };
                *(ushort4v*)&Vt[((size_t)(b * 8 + h) * 64 + dk) * 4096 + s0] = pk;
            }
        }
    }
}

// ---------------------------------------------------------------------------
// Output projection GEMM: A = ctx bf16 [8192][512], out fp32.
// ---------------------------------------------------------------------------
__global__ __launch_bounds__(256) void gemm_out(
    const unsigned short* __restrict__ Actx, const float* __restrict__ W,
    const float* __restrict__ bias, float* __restrict__ Out)
{
    __shared__ unsigned short Alds[128][40];
    __shared__ unsigned short Blds[128][40];

    const int tid  = threadIdx.x;
    const int lane = tid & 63;
    const int wid  = tid >> 6;
    const int wm   = wid >> 1, wn = wid & 1;
    const int bm   = blockIdx.y, bn = blockIdx.x;
    const int l15  = lane & 15;
    const int g    = lane >> 4;
    const int srow = tid >> 1;
    const int scol = (tid & 1) * 16;

    f32x4 acc[4][4];
    #pragma unroll
    for (int m = 0; m < 4; m++)
        #pragma unroll
        for (int n = 0; n < 4; n++)
            acc[m][n] = (f32x4){0.f, 0.f, 0.f, 0.f};

    for (int k0 = 0; k0 < 512; k0 += 32) {
        {
            const unsigned short* A = Actx + (size_t)(bm * 128 + srow) * 512 + k0 + scol;
            ushort8 p0 = ((const ushort8*)A)[0];
            ushort8 p1 = ((const ushort8*)A)[1];
            *(ushort8*)&Alds[srow][scol]     = p0;
            *(ushort8*)&Alds[srow][scol + 8] = p1;
        }
        {
            const float* Bp = W + (size_t)(bn * 128 + srow) * 512 + k0 + scol;
            float4 v0 = ((const float4*)Bp)[0];
            float4 v1 = ((const float4*)Bp)[1];
            float4 v2 = ((const float4*)Bp)[2];
            float4 v3 = ((const float4*)Bp)[3];
            ushort8 p0 = { bfbits(v0.x), bfbits(v0.y), bfbits(v0.z), bfbits(v0.w),
                           bfbits(v1.x), bfbits(v1.y), bfbits(v1.z), bfbits(v1.w) };
            ushort8 p1 = { bfbits(v2.x), bfbits(v2.y), bfbits(v2.z), bfbits(v2.w),
                           bfbits(v3.x), bfbits(v3.y), bfbits(v3.z), bfbits(v3.w) };
            *(ushort8*)&Blds[srow][scol]     = p0;
            *(ushort8*)&Blds[srow][scol + 8] = p1;
        }
        __syncthreads();

        bf16x8 af[4], bfr[4];
        #pragma unroll
        for (int m = 0; m < 4; m++)
            af[m] = *(const bf16x8*)&Alds[wm * 64 + m * 16 + l15][g * 8];
        #pragma unroll
        for (int n = 0; n < 4; n++)
            bfr[n] = *(const bf16x8*)&Blds[wn * 64 + n * 16 + l15][g * 8];
        #pragma unroll
        for (int m = 0; m < 4; m++)
            #pragma unroll
            for (int n = 0; n < 4; n++)
                acc[m][n] = mfma16(af[m], bfr[n], acc[m][n]);
        __syncthreads();
    }

    #pragma unroll
    for (int m = 0; m < 4; m++) {
        const int grow0 = bm * 128 + wm * 64 + m * 16 + (g << 2);
        #pragma unroll
        for (int n = 0; n < 4; n++) {
            const int gcol = bn * 128 + wn * 64 + n * 16 + l15;
            const float bv2 = bias[gcol];
            f32x4 c = acc[m][n];
            #pragma unroll
            for (int r = 0; r < 4; r++)
                Out[(size_t)(grow0 + r) * 512 + gcol] = c[r] + bv2;
        }
    }
}

// ---------------------------------------------------------------------------
// Flash attention, swapped 32x32x16 QK^T, softmax WITHOUT max tracking:
// scores are bounded (|s| <~ 9 in log2 domain, decay/scale pre-folded into
// Qh/Kh), so p = exp2(s) directly; l accumulated per lane; plain-sum split-K
// merge. P->bf16 via cvt_pk + permlane32_swap. 2x-unrolled dbuf loop so all
// LDS addresses are loop-invariant. No branches in the hot loop.
// Grid: 1024 blocks (16 bh x 64 q-tiles), 4 waves = 2 qg x 2 key-halves.
// ---------------------------------------------------------------------------
__global__ __launch_bounds__(256, 4) void attn_decay(
    const unsigned short* __restrict__ Qh, const unsigned short* __restrict__ Kh,
    const unsigned short* __restrict__ Vt, unsigned short* __restrict__ ctx)
{
    // [0,16K): K dbuf | [16K,32K): V dbuf
    // epilogue reuse: Oscr[qg][32][64] f32 at [0,16K); l scratch at [16K,+512)
    __shared__ __align__(16) char LDSB[32768];

    const int tid  = threadIdx.x;
    const int lane = tid & 63;
    const int w    = tid >> 6;
    const int qg   = w >> 1;      // q sub-tile (0..1)
    const int ws   = w & 1;       // key half (0..1)
    const int l31  = lane & 31;
    const int hl   = lane >> 5;

    const int i  = blockIdx.x;
    const int bh = ((i & 7) << 1) | ((i >> 9) & 1);  // XCD swizzle, bijective
    const int qt = (i >> 3) & 63;
    const int h  = bh & 7;
    const int b  = bh >> 3;

    // Q fragments: B-operand, 4 dk-chunks (Qh already scaled by coef*log2e)
    bf16x8 qf[4];
    {
        const unsigned short* Qp =
            Qh + ((size_t)bh * 4096 + qt * 64 + qg * 32 + l31) * 64 + hl * 8;
        #pragma unroll
        for (int c = 0; c < 4; c++)
            qf[c] = *(const bf16x8*)(Qp + c * 16);
    }

    f32x16 o0 = zero16(), o1 = zero16();   // d 0-31 / 32-63
    float lp = 0.f;

    // staging: per-wave pre-swizzled global sources, linear LDS dest
    const char* kgp0; const char* kgp1; const char* vgp0; const char* vgp1;
    int ldsoff0, ldsoff1;
    {
        const size_t kbaseB = (size_t)bh * 4096 * 64 * 2;
        const size_t vbaseB = (size_t)bh * 64 * 4096 * 2;
        const int p0 = w * 2048 + lane * 16;
        const int r0 = p0 >> 7, c0 = p0 & 127, sw0 = (r0 & 7) << 4;
        const int p1 = w * 2048 + 1024 + lane * 16;
        const int r1 = p1 >> 7, c1 = p1 & 127, sw1 = (r1 & 7) << 4;
        kgp0 = (const char*)Kh + kbaseB + (size_t)r0 * 128  + (c0 ^ sw0);
        kgp1 = (const char*)Kh + kbaseB + (size_t)r1 * 128  + (c1 ^ sw1);
        vgp0 = (const char*)Vt + vbaseB + (size_t)r0 * 8192 + (c0 ^ sw0);
        vgp1 = (const char*)Vt + vbaseB + (size_t)r1 * 8192 + (c1 ^ sw1);
        ldsoff0 = w * 2048;
        ldsoff1 = w * 2048 + 1024;
    }
    // prologue: tile 0 -> buf 0
    gload16(kgp0, LDSB + ldsoff0);
    gload16(kgp1, LDSB + ldsoff1);
    gload16(vgp0, LDSB + 16384 + ldsoff0);
    gload16(vgp1, LDSB + 16384 + ldsoff1);
    kgp0 += 8192; kgp1 += 8192; vgp0 += 128; vgp1 += 128;

    const int krow = ws * 32 + l31;
    const int ksw  = (krow & 7) << 4;

#define ATTN_TILE(CUR, KT)                                                        \
    {                                                                             \
        asm volatile("s_waitcnt vmcnt(0)" ::: "memory");                          \
        __syncthreads();                                                          \
        if ((KT) < 63) {                                                          \
            gload16(kgp0, LDSB + ((CUR) ^ 1) * 8192 + ldsoff0);                   \
            gload16(kgp1, LDSB + ((CUR) ^ 1) * 8192 + ldsoff1);                   \
            gload16(vgp0, LDSB + 16384 + ((CUR) ^ 1) * 8192 + ldsoff0);           \
            gload16(vgp1, LDSB + 16384 + ((CUR) ^ 1) * 8192 + ldsoff1);           \
            kgp0 += 8192; kgp1 += 8192; vgp0 += 128; vgp1 += 128;                 \
        }                                                                         \
        const char* kb = LDSB + (CUR) * 8192;                                     \
        const char* vb = LDSB + 16384 + (CUR) * 8192;                             \
        f32x16 s = zero16();                                                      \
        __builtin_amdgcn_s_setprio(1);                                            \
        _Pragma("unroll")                                                         \
        for (int c = 0; c < 4; c++) {                                             \
            bf16x8 kf = *(const bf16x8*)(kb + krow * 128 + ((c * 32 + hl * 16) ^ ksw)); \
            s = mfma32(kf, qf[c], s);                                             \
        }                                                                         \
        __builtin_amdgcn_s_setprio(0);                                            \
        float p[16];                                                              \
        _Pragma("unroll")                                                         \
        for (int r = 0; r < 16; r++) {                                            \
            p[r] = __builtin_amdgcn_exp2f(s[r]);                                  \
            lp += p[r];                                                           \
        }                                                                         \
        unsigned int W0 = cvtpk(p[0], p[1]),   W1 = cvtpk(p[2], p[3]);            \
        unsigned int W2 = cvtpk(p[4], p[5]),   W3 = cvtpk(p[6], p[7]);            \
        unsigned int W4 = cvtpk(p[8], p[9]),   W5 = cvtpk(p[10], p[11]);          \
        unsigned int W6 = cvtpk(p[12], p[13]), W7 = cvtpk(p[14], p[15]);          \
        uint2v r02 = __builtin_amdgcn_permlane32_swap(W0, W2, false, false);      \
        uint2v r13 = __builtin_amdgcn_permlane32_swap(W1, W3, false, false);      \
        uint2v r46 = __builtin_amdgcn_permlane32_swap(W4, W6, false, false);      \
        uint2v r57 = __builtin_amdgcn_permlane32_swap(W5, W7, false, false);      \
        bf16x8 pa0 = __builtin_bit_cast(bf16x8, (uint4v){r02.x, r13.x, r02.y, r13.y}); \
        bf16x8 pa1 = __builtin_bit_cast(bf16x8, (uint4v){r46.x, r57.x, r46.y, r57.y}); \
        __builtin_amdgcn_s_setprio(1);                                            \
        {                                                                         \
            const int vr0  = l31;                                                 \
            const int vsw0 = (vr0 & 7) << 4;                                      \
            bf16x8 va = *(const bf16x8*)(vb + vr0 * 128 + ((ws * 64 + hl * 16) ^ vsw0));      \
            bf16x8 vb2 = *(const bf16x8*)(vb + vr0 * 128 + ((ws * 64 + 32 + hl * 16) ^ vsw0));\
            o0 = mfma32(pa0, va, o0);                                             \
            o0 = mfma32(pa1, vb2, o0);                                            \
            const int vr1  = 32 + l31;                                            \
            const int vsw1 = (vr1 & 7) << 4;                                      \
            bf16x8 vc = *(const bf16x8*)(vb + vr1 * 128 + ((ws * 64 + hl * 16) ^ vsw1));      \
            bf16x8 vd = *(const bf16x8*)(vb + vr1 * 128 + ((ws * 64 + 32 + hl * 16) ^ vsw1)); \
            o1 = mfma32(pa0, vc, o1);                                             \
            o1 = mfma32(pa1, vd, o1);                                             \
        }                                                                         \
        __builtin_amdgcn_s_setprio(0);                                            \
    }

    #pragma unroll 1
    for (int t = 0; t < 32; ++t) {
        const int kt0 = t * 2;
        ATTN_TILE(0, kt0)
        ATTN_TILE(1, kt0 + 1)
    }
#undef ATTN_TILE

    // ---- split-K merge across ws pair (plain sums; no max needed) ----
    float lw = lp + __shfl_xor(lp, 32);   // q-row l31 total over wave's 32 keys
    __syncthreads();                      // (1) all loop LDS reads done
    float* lscr = (float*)(LDSB + 16384);
    if (lane < 32)
        lscr[(qg * 2 + ws) * 32 + lane] = lw;
    __syncthreads();                      // (2) l published
    const float pl2 = lscr[(qg * 2 + (ws ^ 1)) * 32 + l31];
    const float myscale = 1.f / (lw + pl2);
    #pragma unroll
    for (int rc = 0; rc < 4; rc++)
        #pragma unroll
        for (int j = 0; j < 4; j++) {
            const float a = lanepull(myscale, rc * 8 + hl * 4 + j);
            o0[rc * 4 + j] *= a;
            o1[rc * 4 + j] *= a;
        }
    __syncthreads();                      // (3) scratch reads done; reuse [0,16K)
    float* Oscr = (float*)(LDSB + qg * 8192);   // [32][64]
    if (ws == 1) {
        #pragma unroll
        for (int reg = 0; reg < 16; reg++) {
            const int row = (reg & 3) + 8 * (reg >> 2) + 4 * hl;
            Oscr[row * 64 + l31]      = o0[reg];
            Oscr[row * 64 + 32 + l31] = o1[reg];
        }
    }
    __syncthreads();                      // (4) O-halves published
    if (ws == 0) {
        #pragma unroll
        for (int reg = 0; reg < 16; reg++) {
            const int row = (reg & 3) + 8 * (reg >> 2) + 4 * hl;
            const float v0 = o0[reg] + Oscr[row * 64 + l31];
            const float v1 = o1[reg] + Oscr[row * 64 + 32 + l31];
            const int srow_ = qt * 64 + qg * 32 + row;
            const size_t idx = ((size_t)b * 4096 + srow_) * 512 + h * 64;
            ctx[idx + l31]      = bfbits(v0);
            ctx[idx + 32 + l31] = bfbits(v1);
        }
    }
}

// ---------------------------------------------------------------------------
extern "C" void kernel_launch(void* const* d_in, const int* in_sizes, int n_in,
                              void* d_out, int out_size, void* d_ws, size_t ws_size,
                              hipStream_t stream)
{
    (void)in_sizes; (void)n_in; (void)out_size; (void)ws_size;
    const float* q  = (const float*)d_in[0];
    const float* k  = (const float*)d_in[1];
    const float* v  = (const float*)d_in[2];
    const float* Wq = (const float*)d_in[3];
    const float* bq = (const float*)d_in[4];
    const float* Wk = (const float*)d_in[5];
    const float* bk = (const float*)d_in[6];
    const float* Wv = (const float*)d_in[7];
    const float* bv = (const float*)d_in[8];
    const float* Wo = (const float*)d_in[9];
    const float* bo = (const float*)d_in[10];
    const float* td = (const float*)d_in[11];
    const float* sc = (const float*)d_in[12];

    unsigned short* Qh  = (unsigned short*)d_ws;
    unsigned short* Kh  = Qh + (size_t)16 * 4096 * 64;
    unsigned short* Vt  = Kh + (size_t)16 * 4096 * 64;
    unsigned short* ctx = Vt + (size_t)16 * 4096 * 64;

    gemm_qkv<<<dim3(4, 64, 3), 256, 0, stream>>>(q, k, v, Wq, bq, Wk, bk, Wv, bv, td, sc, Qh, Kh, Vt);
    attn_decay<<<dim3(1024), 256, 0, stream>>>(Qh, Kh, Vt, ctx);
    gemm_out<<<dim3(4, 64), 256, 0, stream>>>(ctx, Wo, bo, (float*)d_out);
}